// Round 1
// 277.552 us; speedup vs baseline: 1.1011x; 1.1011x over previous
//
#include <hip/hip_runtime.h>
#include <hip/hip_bf16.h>
#include <stdint.h>

#define N_DIM 2048
#define BATCH_SZ 8192

typedef __bf16 bf16;
typedef __bf16 bf16x4 __attribute__((ext_vector_type(4)));
typedef __bf16 bf16x8 __attribute__((ext_vector_type(8)));
typedef float f32x4 __attribute__((ext_vector_type(4)));

// Async global->LDS, 16B per lane. LDS dest is wave-uniform base + lane*16.
__device__ __forceinline__ void gld16(const bf16* g, bf16* l) {
  __builtin_amdgcn_global_load_lds(
      (const __attribute__((address_space(1))) void*)g,
      (__attribute__((address_space(3))) void*)l, 16, 0, 0);
}

// Build Wb = bf16(W) where W = -S (so exp(W) = Q^T), Wtb = bf16(W^T) = bf16(S).
__global__ void unfold_kernel(const float* __restrict__ Sflat,
                              bf16* __restrict__ Wb,
                              bf16* __restrict__ Wtb) {
  int idx = blockIdx.x * blockDim.x + threadIdx.x;
  int i = idx >> 11;            // row
  int j = idx & (N_DIM - 1);    // col
  float v = 0.0f;               // v = S[i][j]
  if (i < j) {
    int fi = i * (N_DIM - 1) - ((i * (i - 1)) >> 1) + (j - i - 1);
    v = Sflat[fi];
  } else if (i > j) {
    int fi = j * (N_DIM - 1) - ((j * (j - 1)) >> 1) + (i - j - 1);
    v = -Sflat[fi];
  }
  Wb[idx]  = (bf16)(-v);   // W = -S
  Wtb[idx] = (bf16)(v);    // W^T = S
}

// fp32 -> bf16 elementwise (vectorized x4)
__global__ void cast_kernel(const float* __restrict__ in, bf16* __restrict__ out) {
  int t = blockIdx.x * blockDim.x + threadIdx.x;
  float4 v = ((const float4*)in)[t];
  bf16x4 o;
  o.x = (bf16)v.x; o.y = (bf16)v.y; o.z = (bf16)v.z; o.w = (bf16)v.w;
  ((bf16x4*)out)[t] = o;
}

// ---------------------------------------------------------------------------
// Weight GEMMs (unchanged): C(MxN) = A(MxK) @ Bt(NxK)^T, bf16 in, fp32 acc.
// MODE 1: O1 = bf16(acc) [W2];  O2 = bf16(I/2 - W/6 + acc/24) [B^T operand]
// MODE 2: O1 = bf16(acc + I + W)                          (Q^T)
template <int MODE, int TM>
__global__ __launch_bounds__(256) void gemm_bt(
    const bf16* __restrict__ A, const bf16* __restrict__ Bt,
    float* __restrict__ Cf, bf16* __restrict__ O1, bf16* __restrict__ O2,
    const bf16* __restrict__ Wb,
    int M, int N, int K) {
  constexpr int MI  = TM / 32;    // m-fragments per wave
  constexpr int ACH = TM / 64;    // 64-row staging chunks for A
  __shared__ __align__(16) bf16 As[TM * 32];
  __shared__ __align__(16) bf16 Bs[128 * 32];

  const int tid  = threadIdx.x;
  const int lane = tid & 63;
  const int wave = tid >> 6;
  const int wr   = wave >> 1;
  const int wc   = wave & 1;
  const int quad = lane >> 4;
  const int l16  = lane & 15;
  const int m0 = blockIdx.y * TM;
  const int n0 = blockIdx.x * 128;

  const int srow = wave * 16 + (lane >> 2);
  const int sseg = (((lane & 3) ^ ((lane >> 3) & 3)) * 8);

  const bf16* gA[ACH];
  bf16* lA[ACH];
#pragma unroll
  for (int c = 0; c < ACH; ++c) {
    gA[c] = A + (size_t)(m0 + c * 64 + srow) * K + sseg;
    lA[c] = As + (c * 64 + wave * 16) * 32;
  }
  const bf16* gB[2];
  bf16* lB[2];
#pragma unroll
  for (int c = 0; c < 2; ++c) {
    gB[c] = Bt + (size_t)(n0 + c * 64 + srow) * K + sseg;
    lB[c] = Bs + (c * 64 + wave * 16) * 32;
  }

  f32x4 acc[MI][4] = {};
  const int xsw = (l16 >> 1) & 3;   // reader-side swizzle index

  for (int k0 = 0; k0 < K; k0 += 32) {
    __syncthreads();
#pragma unroll
    for (int c = 0; c < ACH; ++c) { gld16(gA[c], lA[c]); gA[c] += 32; }
#pragma unroll
    for (int c = 0; c < 2;   ++c) { gld16(gB[c], lB[c]); gB[c] += 32; }
    __syncthreads();

    bf16x8 af[MI], bfr[4];
#pragma unroll
    for (int mi = 0; mi < MI; ++mi)
      af[mi] = *(const bf16x8*)&As[(wr * (TM / 2) + mi * 16 + l16) * 32 +
                                   ((quad ^ xsw) * 8)];
#pragma unroll
    for (int ni = 0; ni < 4; ++ni)
      bfr[ni] = *(const bf16x8*)&Bs[(wc * 64 + ni * 16 + l16) * 32 +
                                    ((quad ^ xsw) * 8)];
#pragma unroll
    for (int mi = 0; mi < MI; ++mi)
#pragma unroll
      for (int ni = 0; ni < 4; ++ni)
        acc[mi][ni] = __builtin_amdgcn_mfma_f32_16x16x32_bf16(
            af[mi], bfr[ni], acc[mi][ni], 0, 0, 0);
  }

  // Epilogue. C/D layout: col = lane&15, row = quad*4 + reg.
#pragma unroll
  for (int mi = 0; mi < MI; ++mi) {
    const int rbase = m0 + wr * (TM / 2) + mi * 16 + quad * 4;
#pragma unroll
    for (int ni = 0; ni < 4; ++ni) {
      const int col = n0 + wc * 64 + ni * 16 + l16;
#pragma unroll
      for (int r = 0; r < 4; ++r) {
        const int row = rbase + r;
        const size_t idx = (size_t)row * N + col;
        const float v = acc[mi][ni][r];
        if (MODE == 0) {
          Cf[idx] = v;
        } else if (MODE == 1) {
          O1[idx] = (bf16)v;
          const float w = (float)Wb[idx];
          const float d = (row == col) ? 1.0f : 0.0f;
          O2[idx] = (bf16)(0.5f * d - (1.0f / 6.0f) * w + (1.0f / 24.0f) * v);
        } else {  // MODE 2: Q^T = acc + I + W
          const float w = (float)Wb[idx];
          const float d = (row == col) ? 1.0f : 0.0f;
          O1[idx] = (bf16)(v + d + w);
        }
      }
    }
  }
}

// ---------------------------------------------------------------------------
// G3 kernel: C(MxN) f32 = A(MxK) @ Bt(NxK)^T, bf16 in.
// 256x256 tile, 8 waves (2M x 4N), BK=32, 4-deep LDS ring (128 KiB),
// global_load_lds staging 3 tiles ahead, counted vmcnt (never 0 in steady
// state), one raw s_barrier per K-tile, setprio around the MFMA cluster.
// Requires: N == gridDim.x*256 with gridDim.x == 8, K % 128 == 0, K/32 >= 4.
__global__ __launch_bounds__(512, 2) void gemm256(
    const bf16* __restrict__ A, const bf16* __restrict__ Bt,
    float* __restrict__ Cf, int M, int N, int K) {
  __shared__ __align__(16) bf16 As[4 * 256 * 32];   // 64 KB
  __shared__ __align__(16) bf16 Bs[4 * 256 * 32];   // 64 KB

  const int tid  = threadIdx.x;
  const int lane = tid & 63;
  const int wave = tid >> 6;     // 0..7
  const int wr   = wave >> 2;    // 0..1  M-half
  const int wc   = wave & 3;     // 0..3  N-quarter
  const int quad = lane >> 4;
  const int l16  = lane & 15;

  // Bijective XCD swizzle (nwg = 256 divisible by 8): XCD x gets 32
  // consecutive tile ids = 4 full A-panel rows -> A fetched once per XCD.
  const int nwg    = gridDim.x * gridDim.y;
  const int linear = blockIdx.y * gridDim.x + blockIdx.x;
  const int wg = (linear & 7) * (nwg >> 3) + (linear >> 3);
  const int bx = wg & 7;         // gridDim.x == 8 (N == 2048)
  const int by = wg >> 3;
  const int m0 = by * 256;
  const int n0 = bx * 256;

  // Staging: 32 chunks of 16 rows per operand per K-tile; wave w stages
  // chunks {w, w+8} of A and of B (4 gld16 per thread per tile).
  // Lane l -> row l>>2 of chunk, source slot (l&3)^((l>>3)&3) so that
  // LDS[row][s] = G[row][s ^ ((row>>1)&3)]  (same scheme as gemm_bt,
  // verified conflict-free).
  const int srow  = lane >> 2;
  const int sslot = (lane & 3) ^ ((lane >> 3) & 3);
  const bf16* pA1 = A  + (size_t)(m0 + wave * 16 + srow) * K + sslot * 8;
  const bf16* pA2 = pA1 + (size_t)128 * K;
  const bf16* pB1 = Bt + (size_t)(n0 + wave * 16 + srow) * K + sslot * 8;
  const bf16* pB2 = pB1 + (size_t)128 * K;
  bf16* lA1 = As + wave * 512;          // + buf*8192
  bf16* lA2 = As + wave * 512 + 4096;
  bf16* lB1 = Bs + wave * 512;
  bf16* lB2 = Bs + wave * 512 + 4096;

  const int NT = K >> 5;   // K-tiles of 32

  // Prologue: stage tiles 0,1,2 into ring buffers 0,1,2 (12 loads/thread),
  // then wait for tile 0 only (8 loads may stay in flight).
#pragma unroll
  for (int tt = 0; tt < 3; ++tt) {
    gld16(pA1 + tt * 32, lA1 + tt * 8192);
    gld16(pA2 + tt * 32, lA2 + tt * 8192);
    gld16(pB1 + tt * 32, lB1 + tt * 8192);
    gld16(pB2 + tt * 32, lB2 + tt * 8192);
  }
  asm volatile("s_waitcnt vmcnt(8)" ::: "memory");
  __builtin_amdgcn_s_barrier();
  __builtin_amdgcn_sched_barrier(0);

  f32x4 acc[8][4] = {};
  const int rswz = (quad ^ ((l16 >> 1) & 3)) * 8;  // reader swizzle (elems)
  const int arow = wr * 128 + l16;
  const int brow = wc * 64 + l16;

  size_t kpre = 96;   // element k-offset of tile t+3 at t=0

#pragma unroll 1
  for (int t4 = 0; t4 < NT; t4 += 4) {
#pragma unroll
    for (int u = 0; u < 4; ++u) {
      const int t = t4 + u;
      // Issue staging for tile t+3 -> buffer (u+3)&3 (that buffer's last
      // reads finished before the end-of-(t-1) barrier).
      if (t + 3 < NT) {
        const int b = (u + 3) & 3;
        const size_t ko = kpre + (size_t)u * 32;
        gld16(pA1 + ko, lA1 + b * 8192);
        gld16(pA2 + ko, lA2 + b * 8192);
        gld16(pB1 + ko, lB1 + b * 8192);
        gld16(pB2 + ko, lB2 + b * 8192);
      }
      // Compute tile t from buffer u.
      const bf16* ab = As + u * 8192;
      const bf16* bb = Bs + u * 8192;
      bf16x8 af[8], bfr[4];
#pragma unroll
      for (int mi = 0; mi < 8; ++mi)
        af[mi] = *(const bf16x8*)&ab[(arow + mi * 16) * 32 + rswz];
#pragma unroll
      for (int ni = 0; ni < 4; ++ni)
        bfr[ni] = *(const bf16x8*)&bb[(brow + ni * 16) * 32 + rswz];
      __builtin_amdgcn_s_setprio(1);
#pragma unroll
      for (int mi = 0; mi < 8; ++mi)
#pragma unroll
        for (int ni = 0; ni < 4; ++ni)
          acc[mi][ni] = __builtin_amdgcn_mfma_f32_16x16x32_bf16(
              af[mi], bfr[ni], acc[mi][ni], 0, 0, 0);
      __builtin_amdgcn_s_setprio(0);
      // K-tile boundary: retire tile t+1's 4 loads, leave the rest in
      // flight. In flight at this point: up to t+2 (4) + t+3 (4) = 8.
      if (t < NT - 1) {
        if (t < NT - 3)
          asm volatile("s_waitcnt vmcnt(8)" ::: "memory");
        else if (t == NT - 3)
          asm volatile("s_waitcnt vmcnt(4)" ::: "memory");
        else
          asm volatile("s_waitcnt vmcnt(0)" ::: "memory");
        __builtin_amdgcn_sched_barrier(0);
        __builtin_amdgcn_s_barrier();
        __builtin_amdgcn_sched_barrier(0);
      }
    }
    kpre += 128;
  }

  // Epilogue: C/D layout col = lane&15, row = quad*4 + reg.
#pragma unroll
  for (int mi = 0; mi < 8; ++mi) {
    const int r0 = m0 + wr * 128 + mi * 16 + quad * 4;
#pragma unroll
    for (int ni = 0; ni < 4; ++ni) {
      const int col = n0 + wc * 64 + ni * 16 + l16;
#pragma unroll
      for (int r = 0; r < 4; ++r)
        Cf[(size_t)(r0 + r) * N + col] = acc[mi][ni][r];
    }
  }
}

extern "C" void kernel_launch(void* const* d_in, const int* in_sizes, int n_in,
                              void* d_out, int out_size, void* d_ws, size_t ws_size,
                              hipStream_t stream) {
  const float* X     = (const float*)d_in[0];
  const float* Sflat = (const float*)d_in[1];
  float* out = (float*)d_out;
  char* ws = (char*)d_ws;

  // Workspace (72 MB total):
  bf16* Xb   = (bf16*)(ws);                 // 32 MB  bf16(X)
  bf16* Wb   = (bf16*)(ws + (32u << 20));   //  8 MB  bf16(W),   W = -S
  bf16* Wtb  = (bf16*)(ws + (40u << 20));   //  8 MB  bf16(W^T)
  bf16* W2b  = (bf16*)(ws + (48u << 20));   //  8 MB  bf16(W^2)
  bf16* Btm  = (bf16*)(ws + (56u << 20));   //  8 MB  bf16(B^T) operand for G2
  bf16* Qtb  = (bf16*)(ws + (64u << 20));   //  8 MB  bf16(Q^T)

  unfold_kernel<<<(N_DIM * N_DIM) / 256, 256, 0, stream>>>(Sflat, Wb, Wtb);
  cast_kernel<<<(BATCH_SZ * N_DIM / 4) / 256, 256, 0, stream>>>(X, Xb);

  // Weight GEMMs: 64x128 tiles -> 512 blocks = 2 blocks/CU.
  const dim3 gW(N_DIM / 128, N_DIM / 64);
  // G1: W2 = W @ W;  epilogue also emits B^T = I/2 - W/6 + W2/24.
  gemm_bt<1, 64><<<gW, 256, 0, stream>>>(Wb, Wtb, nullptr, W2b, Btm,
                                         Wb, N_DIM, N_DIM, N_DIM);
  // G2: Q^T = I + W + W2 @ B   (Bt operand = B^T).
  gemm_bt<2, 64><<<gW, 256, 0, stream>>>(W2b, Btm, nullptr, Qtb, nullptr,
                                         Wb, N_DIM, N_DIM, N_DIM);
  // G3: out = X @ Q  (Bt = Q^T row-major). 256x256 tiles -> 256 blocks,
  // 1 block/CU, pipelined ring-buffer kernel.
  gemm256<<<dim3(N_DIM / 256, BATCH_SZ / 256), 512, 0, stream>>>(
      Xb, Qtb, out, BATCH_SZ, N_DIM, N_DIM);
}